// Round 4
// baseline (328.434 us; speedup 1.0000x reference)
//
#include <hip/hip_runtime.h>
#include <hip/hip_bf16.h>

#define NQ   13
#define DIM  8192
#define NT   256
#define PI_F 3.14159265358979323846f

// range-reduced fast sincos: reduce to [-pi, pi] before native sin/cos
__device__ __forceinline__ void rsincos(float x, float* s, float* c) {
  const float INV2PI = 0.15915494309189535f;
  const float TWOPI  = 6.283185307179586f;
  float r = x * INV2PI;
  r -= rintf(r);            // [-0.5, 0.5] revolutions
  float ang = r * TWOPI;    // [-pi, pi]
  *s = __sinf(ang);
  *c = __cosf(ang);
}

__global__ __launch_bounds__(NT) void qc_kernel(
    const float* __restrict__ xin,
    const float* __restrict__ thin,
    const float* __restrict__ bin,
    float* __restrict__ out)
{
  __shared__ float sRe[DIM], sIm[DIM];      // 64 KB state
  __shared__ float xq[NQ], aq[NQ];          // x, pi-x by qubit index
  __shared__ float gCA[65], gSA[65];        // cos/sin(a/2) per gate l*13+q
  __shared__ float gEMR[65], gEMI[65];      // em = exp(-i b/2) per gate
  __shared__ float sA2;
  __shared__ float red[NT / 64];

  const int t = threadIdx.x;
  const int b = blockIdx.x;

  if (t < NQ) { float xv = xin[b * NQ + t]; xq[t] = xv; aq[t] = PI_F - xv; }
  if (t < 65) {
    float av = thin[2 * t], bv = thin[2 * t + 1];
    gCA[t]  = cosf(0.5f * av);
    gSA[t]  = sinf(0.5f * av);
    gEMR[t] = cosf(0.5f * bv);
    gEMI[t] = -sinf(0.5f * bv);
  }
  __syncthreads();
  if (t == 0) { float s = 0.f; for (int q = 0; q < NQ; q++) s += aq[q] * aq[q]; sA2 = s; }
  __syncthreads();

  const float A2 = sA2;

  // ---- init: psi(i) = 2^-13 * exp(i*phi(i))
  // (2^-13 = initial DIM^-1/2 times the fwht's 2^-13/2 normalization)
  for (int k = 0; k < DIM / NT; k++) {
    int i = t + NT * k;
    float u = 0.f, v = 0.f;
    for (int q = 0; q < NQ; q++) {
      float s = ((i >> (NQ - 1 - q)) & 1) ? -1.f : 1.f;   // SIGNS[i,q]
      u = fmaf(xq[q], s, u);
      v = fmaf(aq[q], s, v);
    }
    float phi = u + 0.5f * (v * v - A2);
    float sn, cs; rsincos(phi, &sn, &cs);
    sRe[i] = cs * (1.0f / 8192.0f);
    sIm[i] = sn * (1.0f / 8192.0f);
  }
  __syncthreads();

  // ---- FWHT: unnormalized H butterfly on every bit (norm absorbed above)
  for (int p = 0; p < NQ; p++) {
    for (int k = 0; k < DIM / (2 * NT); k++) {
      int m  = t + NT * k;
      int i0 = ((m >> p) << (p + 1)) | (m & ((1 << p) - 1));
      int i1 = i0 | (1 << p);
      float r0 = sRe[i0], q0 = sIm[i0], r1 = sRe[i1], q1 = sIm[i1];
      sRe[i0] = r0 + r1; sIm[i0] = q0 + q1;
      sRe[i1] = r0 - r1; sIm[i1] = q0 - q1;
    }
    __syncthreads();
  }

  // ---- second feature-map diagonal: psi *= exp(i*phi(i))
  for (int k = 0; k < DIM / NT; k++) {
    int i = t + NT * k;
    float u = 0.f, v = 0.f;
    for (int q = 0; q < NQ; q++) {
      float s = ((i >> (NQ - 1 - q)) & 1) ? -1.f : 1.f;
      u = fmaf(xq[q], s, u);
      v = fmaf(aq[q], s, v);
    }
    float phi = u + 0.5f * (v * v - A2);
    float sn, cs; rsincos(phi, &sn, &cs);
    float r = sRe[i], q = sIm[i];
    sRe[i] = r * cs - q * sn;
    sIm[i] = r * sn + q * cs;
  }
  __syncthreads();

  // ---- variational layers, faithful to reference (no fusion)
  for (int l = 0; l < 5; l++) {
    if (l > 0) {
      // psi *= ENT  (sign = (-1)^{# adjacent set-bit pairs})
      for (int k = 0; k < DIM / NT; k++) {
        int i = t + NT * k;
        if (__popc(i & (i >> 1)) & 1) { sRe[i] = -sRe[i]; sIm[i] = -sIm[i]; }
      }
      __syncthreads();
    }
    for (int q = 0; q < NQ; q++) {
      int g = l * NQ + q;
      float ca = gCA[g], sa = gSA[g], er = gEMR[g], ei = gEMI[g];
      int p = NQ - 1 - q;   // qubit q acts on bit 12-q
      for (int k = 0; k < DIM / (2 * NT); k++) {
        int m  = t + NT * k;
        int i0 = ((m >> p) << (p + 1)) | (m & ((1 << p) - 1));
        int i1 = i0 | (1 << p);
        float r0 = sRe[i0], q0 = sIm[i0], r1 = sRe[i1], q1 = sIm[i1];
        // Ry part (real coefficients)
        float t0r = ca * r0 - sa * r1, t0i = ca * q0 - sa * q1;
        float t1r = sa * r0 + ca * r1, t1i = sa * q0 + ca * q1;
        // Rz part: out0 = em*t0, out1 = conj(em)*t1, em = er + i*ei
        sRe[i0] = er * t0r - ei * t0i;  sIm[i0] = er * t0i + ei * t0r;
        sRe[i1] = er * t1r + ei * t1i;  sIm[i1] = er * t1i - ei * t1r;
      }
      __syncthreads();
    }
  }

  // ---- readout: logit = sum_i |psi(i)|^2 * (-1)^popc(i) + bias
  float acc = 0.f;
  for (int k = 0; k < DIM / NT; k++) {
    int i = t + NT * k;
    float p2 = sRe[i] * sRe[i] + sIm[i] * sIm[i];
    acc += (__popc(i) & 1) ? -p2 : p2;
  }
  #pragma unroll
  for (int off = 32; off > 0; off >>= 1) acc += __shfl_down(acc, off, 64);
  if ((t & 63) == 0) red[t >> 6] = acc;
  __syncthreads();
  if (t == 0) {
    float logit = red[0] + red[1] + red[2] + red[3] + bin[0];
    out[b * 2 + 0] = -logit;
    out[b * 2 + 1] = logit;
  }
}

extern "C" void kernel_launch(void* const* d_in, const int* in_sizes, int n_in,
                              void* d_out, int out_size, void* d_ws, size_t ws_size,
                              hipStream_t stream) {
  const float* x  = (const float*)d_in[0];
  const float* th = (const float*)d_in[1];
  const float* bi = (const float*)d_in[2];
  float* out = (float*)d_out;
  int B = in_sizes[0] / NQ;   // 512
  qc_kernel<<<B, NT, 0, stream>>>(x, th, bi, out);
}

// Round 5
// 109.973 us; speedup vs baseline: 2.9865x; 2.9865x over previous
//
#include <hip/hip_runtime.h>
#include <hip/hip_bf16.h>

#define NQ   13
#define DIM  8192
#define PI_F 3.14159265358979323846f
#define NT   256     // threads per block (4 waves)
#define NAMP 32      // amplitudes per thread

// LDS slot with +1 float pad per 32 -> at most 2-way bank aliasing (free) for
// all three pass patterns
__device__ __forceinline__ int lslot(int i) { return i + (i >> 5); }
#define NSLOT (DIM + (DIM >> 5))   // 8448 floats per component array

// range-reduced fast sincos: reduce to [-pi, pi] before native sin/cos
__device__ __forceinline__ void rsincos(float x, float* s, float* c) {
  const float INV2PI = 0.15915494309189535f;
  const float TWOPI  = 6.283185307179586f;
  float r = x * INV2PI;
  r -= rintf(r);            // [-0.5, 0.5] revolutions
  float ang = r * TWOPI;    // [-pi, pi]
  *s = __sinf(ang);
  *c = __cosf(ang);
}

// ---------------------------------------------------------------------------
// Pass patterns: each thread owns 32 amps varying in 5 bit positions.
//  PAT0: i = (t<<5) | j                      (j bits -> i bits 0..4)
//  PAT1: i = ((t>>5)<<10) | (j<<5) | (t&31)  (j bits -> i bits 5..9)
//  PAT2: i = ((j>>2)<<10) | (t<<2) | (j&3)   (j bits 2..4 -> i bits 10..12,
//                                             j bits 0..1 -> i bits 0..1)
// ---------------------------------------------------------------------------
template<int PAT>
__device__ __forceinline__ int ampIndex(int t, int j) {
  if constexpr (PAT == 0) return (t << 5) | j;
  else if constexpr (PAT == 1) return ((t >> 5) << 10) | (j << 5) | (t & 31);
  else return ((j >> 2) << 10) | (t << 2) | (j & 3);
}

// s[j] = bias + sum over set bits p of i(t,j) of w[p]   (w indexed by bit pos)
template<int PAT>
__device__ __forceinline__ void buildTree(const float* __restrict__ w, float bias,
                                          int t, float* s) {
  float base = bias;
  if constexpr (PAT == 0) {          // base bits: i bits 5..12 = t bits 0..7
    #pragma unroll
    for (int k = 0; k < 8; k++) base += ((t >> k) & 1) ? w[5 + k] : 0.0f;
  } else if constexpr (PAT == 1) {   // base: i bits 0..4 = t bits 0..4; 10..12 = t bits 5..7
    #pragma unroll
    for (int k = 0; k < 5; k++) base += ((t >> k) & 1) ? w[k] : 0.0f;
    #pragma unroll
    for (int k = 0; k < 3; k++) base += ((t >> (5 + k)) & 1) ? w[10 + k] : 0.0f;
  } else {                           // base: i bits 2..9 = t bits 0..7
    #pragma unroll
    for (int k = 0; k < 8; k++) base += ((t >> k) & 1) ? w[2 + k] : 0.0f;
  }
  constexpr int P[5] = { (PAT == 1) ? 5 : 0,
                         (PAT == 1) ? 6 : 1,
                         (PAT == 0) ? 2 : ((PAT == 1) ? 7 : 10),
                         (PAT == 0) ? 3 : ((PAT == 1) ? 8 : 11),
                         (PAT == 0) ? 4 : ((PAT == 1) ? 9 : 12) };
  s[0] = base;
  #pragma unroll
  for (int k = 0; k < 5; k++) {
    float wp = w[P[k]];
    #pragma unroll
    for (int m = 0; m < (1 << k); m++) s[m | (1 << k)] = s[m] + wp;
  }
}

template<int PAT>
__device__ __forceinline__ void loadAmps(const float* __restrict__ sRe,
                                         const float* __restrict__ sIm,
                                         int t, float* re, float* im) {
  #pragma unroll
  for (int j = 0; j < NAMP; j++) {
    int a = lslot(ampIndex<PAT>(t, j));
    re[j] = sRe[a]; im[j] = sIm[a];
  }
}

template<int PAT>
__device__ __forceinline__ void storeAmps(float* __restrict__ sRe,
                                          float* __restrict__ sIm,
                                          int t, const float* re, const float* im) {
  #pragma unroll
  for (int j = 0; j < NAMP; j++) {
    int a = lslot(ampIndex<PAT>(t, j));
    sRe[a] = re[j]; sIm[a] = im[j];
  }
}

// Hadamard butterfly (unnormalized) on register bit KB
template<int KB>
__device__ __forceinline__ void fwht_bit(float* re, float* im) {
  #pragma unroll
  for (int j = 0; j < NAMP; j++) if (!(j & (1 << KB))) {
    int j1 = j | (1 << KB);
    float r0 = re[j], i0 = im[j], r1 = re[j1], i1 = im[j1];
    re[j]  = r0 + r1; im[j]  = i0 + i1;
    re[j1] = r0 - r1; im[j1] = i0 - i1;
  }
}
__device__ __forceinline__ void fwht_all5(float* re, float* im) {
  fwht_bit<0>(re, im); fwht_bit<1>(re, im); fwht_bit<2>(re, im);
  fwht_bit<3>(re, im); fwht_bit<4>(re, im);
}

// Ry on register bit KB: [a0,a1] -> [ca*a0 - sa*a1, sa*a0 + ca*a1]
// (bit==0 is qubit state 0; Rz parts are deferred into diagonals)
template<int KB>
__device__ __forceinline__ void applyRy(float* re, float* im, float ca, float sa) {
  #pragma unroll
  for (int j = 0; j < NAMP; j++) if (!(j & (1 << KB))) {
    int j1 = j | (1 << KB);
    float r0 = re[j], i0 = im[j], r1 = re[j1], i1 = im[j1];
    re[j]  = ca * r0 - sa * r1;  im[j]  = ca * i0 - sa * i1;
    re[j1] = sa * r0 + ca * r1;  im[j1] = sa * i0 + ca * i1;
  }
}

// psi *= ENT(i) * exp(i * rho(i)), rho from tree over wb (Rz halves)
template<int PAT>
__device__ __forceinline__ void applyDiag(float* re, float* im,
                                          const float* __restrict__ wb,
                                          float bias, int t) {
  float rho[NAMP];
  buildTree<PAT>(wb, bias, t, rho);
  #pragma unroll
  for (int j = 0; j < NAMP; j++) {
    int i = ampIndex<PAT>(t, j);
    float sn, cs;
    rsincos(rho[j], &sn, &cs);
    float ent = (__popc(i & (i >> 1)) & 1) ? -1.0f : 1.0f;
    cs *= ent; sn *= ent;
    float r = re[j], q = im[j];
    re[j] = r * cs - q * sn;
    im[j] = r * sn + q * cs;
  }
}

__global__ __launch_bounds__(NT, 2) void qc_kernel(
    const float* __restrict__ xin,
    const float* __restrict__ thin,
    const float* __restrict__ bin,
    float* __restrict__ out) {
  __shared__ float sRe[NSLOT];
  __shared__ float sIm[NSLOT];
  __shared__ float gCA[65], gSA[65];   // cos/sin(a/2) per gate l*13+q
  __shared__ float gBbit[65];          // b_{l,q} stored at [l*13 + bitpos], bit p = 12-q
  __shared__ float wX[13], wA[13];     // -2*x_{12-p}, -2*a_{12-p} indexed by bit p
  __shared__ float cons[8];            // 0:X 1:A 2:A2 3..7: -0.5*sum_q b_{l,q}
  __shared__ float red[NT / 64];

  const int t = threadIdx.x;
  const int b = blockIdx.x;

  if (t < NQ) {
    float xq = xin[b * NQ + t];
    float aq = PI_F - xq;
    wX[12 - t] = -2.0f * xq;
    wA[12 - t] = -2.0f * aq;
  }
  if (t < 65) {
    float av = thin[2 * t];
    float bv = thin[2 * t + 1];
    gCA[t] = cosf(0.5f * av);
    gSA[t] = sinf(0.5f * av);
    int l = t / NQ, q = t % NQ;
    gBbit[l * NQ + (12 - q)] = bv;
  }
  __syncthreads();
  if (t == 0) {
    float X = 0.f, A = 0.f, A2 = 0.f;
    for (int p = 0; p < NQ; p++) {
      float xq = -0.5f * wX[p], aq = -0.5f * wA[p];
      X += xq; A += aq; A2 += aq * aq;
    }
    cons[0] = X; cons[1] = A; cons[2] = A2;
    for (int l = 0; l < 5; l++) {
      float s = 0.f;
      for (int p = 0; p < NQ; p++) s += gBbit[l * NQ + p];
      cons[3 + l] = -0.5f * s;
    }
  }
  __syncthreads();

  float re[NAMP], im[NAMP];

  // ---- Pass 0 (PAT0): psi = exp(i*phi(i)); FWHT bits 0..4; store
  {
    float u[NAMP], v[NAMP];
    buildTree<0>(wX, cons[0], t, u);
    buildTree<0>(wA, cons[1], t, v);
    float A2 = cons[2];
    #pragma unroll
    for (int j = 0; j < NAMP; j++) {
      float phi = u[j] + 0.5f * (v[j] * v[j] - A2);
      float sn, cs; rsincos(phi, &sn, &cs);
      re[j] = cs; im[j] = sn;
    }
    fwht_all5(re, im);
    storeAmps<0>(sRe, sIm, t, re, im);
  }
  __syncthreads();

  // ---- Pass 1 (PAT1): FWHT bits 5..9
  loadAmps<1>(sRe, sIm, t, re, im);
  fwht_all5(re, im);
  storeAmps<1>(sRe, sIm, t, re, im);
  __syncthreads();

  // ---- Pass 2 (PAT2): FWHT bits 10..12, then second feature-map diagonal d
  loadAmps<2>(sRe, sIm, t, re, im);
  fwht_bit<2>(re, im); fwht_bit<3>(re, im); fwht_bit<4>(re, im);
  {
    float u[NAMP], v[NAMP];
    buildTree<2>(wX, cons[0], t, u);
    buildTree<2>(wA, cons[1], t, v);
    float A2 = cons[2];
    #pragma unroll
    for (int j = 0; j < NAMP; j++) {
      float phi = u[j] + 0.5f * (v[j] * v[j] - A2);
      float sn, cs; rsincos(phi, &sn, &cs);
      float r = re[j], q = im[j];
      re[j] = r * cs - q * sn;
      im[j] = r * sn + q * cs;
    }
  }
  storeAmps<2>(sRe, sIm, t, re, im);
  __syncthreads();

  // ---- Variational layers: Ry only; Rz(b_{l-1})+ENT fused into one diagonal
  float acc = 0.0f;
  for (int l = 0; l < 5; l++) {
    const int g = l * NQ;
    // pass A: bits 0..4  (qubits 12..8)
    loadAmps<0>(sRe, sIm, t, re, im);
    if (l > 0) applyDiag<0>(re, im, gBbit + (l - 1) * NQ, cons[3 + (l - 1)], t);
    applyRy<0>(re, im, gCA[g + 12], gSA[g + 12]);
    applyRy<1>(re, im, gCA[g + 11], gSA[g + 11]);
    applyRy<2>(re, im, gCA[g + 10], gSA[g + 10]);
    applyRy<3>(re, im, gCA[g + 9],  gSA[g + 9]);
    applyRy<4>(re, im, gCA[g + 8],  gSA[g + 8]);
    storeAmps<0>(sRe, sIm, t, re, im);
    __syncthreads();
    // pass B: bits 5..9  (qubits 7..3)
    loadAmps<1>(sRe, sIm, t, re, im);
    applyRy<0>(re, im, gCA[g + 7], gSA[g + 7]);
    applyRy<1>(re, im, gCA[g + 6], gSA[g + 6]);
    applyRy<2>(re, im, gCA[g + 5], gSA[g + 5]);
    applyRy<3>(re, im, gCA[g + 4], gSA[g + 4]);
    applyRy<4>(re, im, gCA[g + 3], gSA[g + 3]);
    storeAmps<1>(sRe, sIm, t, re, im);
    __syncthreads();
    // pass C: bits 10..12 (qubits 2..0); final layer fuses readout
    loadAmps<2>(sRe, sIm, t, re, im);
    applyRy<2>(re, im, gCA[g + 2], gSA[g + 2]);
    applyRy<3>(re, im, gCA[g + 1], gSA[g + 1]);
    applyRy<4>(re, im, gCA[g + 0], gSA[g + 0]);
    if (l < 4) {
      storeAmps<2>(sRe, sIm, t, re, im);
      __syncthreads();
    } else {
      // trailing Rz(b4) is diagonal -> invisible in |psi|^2; readout here
      #pragma unroll
      for (int j = 0; j < NAMP; j++) {
        int i = ampIndex<2>(t, j);
        float p = re[j] * re[j] + im[j] * im[j];
        acc += (__popc(i) & 1) ? -p : p;
      }
    }
  }

  // block reduction of parity-weighted probability (raw scale 2^26)
  #pragma unroll
  for (int off = 32; off > 0; off >>= 1) acc += __shfl_down(acc, off, 64);
  if ((t & 63) == 0) red[t >> 6] = acc;
  __syncthreads();
  if (t == 0) {
    float total = red[0] + red[1] + red[2] + red[3];
    float logit = total * (1.0f / 67108864.0f) + bin[0];
    out[b * 2 + 0] = -logit;
    out[b * 2 + 1] = logit;
  }
}

extern "C" void kernel_launch(void* const* d_in, const int* in_sizes, int n_in,
                              void* d_out, int out_size, void* d_ws, size_t ws_size,
                              hipStream_t stream) {
  const float* x  = (const float*)d_in[0];
  const float* th = (const float*)d_in[1];
  const float* bi = (const float*)d_in[2];
  float* out = (float*)d_out;
  int B = in_sizes[0] / NQ;   // 512
  qc_kernel<<<B, NT, 0, stream>>>(x, th, bi, out);
}